// Round 11
// baseline (155.812 us; speedup 1.0000x reference)
//
#include <hip/hip_runtime.h>
#include <hip/hip_bf16.h>

typedef short short8 __attribute__((ext_vector_type(8)));
typedef float float4v __attribute__((ext_vector_type(4)));

#define NIMG 32
#define CIN 256
#define COUT 256
#define HH 56
#define WW 56
#define HP 58
#define WP 58
#define PIXIMG (HH * WW)          /* 3136 */
#define QIMG (HP * WP)            /* 3364: padded-grid pixels per image */
#define QTOT (NIMG * QIMG)        /* 107648: total padded-grid positions */
#define NTILE (QTOT / 128)        /* 841 tiles of 128 padded positions */
#define OUTSTRIDE_N (COUT * PIXIMG)
#define TR_BLOCKS (NIMG * HP * 4) /* 7424 transpose blocks in k_pre */

static constexpr size_t XT_ELEMS = (size_t)QTOT * CIN;     // bf16
static constexpr size_t WT_ELEMS = (size_t)9 * COUT * CIN; // bf16

// fp32 -> bf16 bits, round-to-nearest-even (finite inputs only)
static __device__ __forceinline__ unsigned short f2bf(float f) {
    unsigned int u = __builtin_bit_cast(unsigned int, f);
    u = (u + 0x7fffu + ((u >> 16) & 1u)) >> 16;
    return (unsigned short)u;
}

// async global(16B/lane) -> LDS (wave-uniform base + lane*16)
static __device__ __forceinline__ void gl16(const unsigned short* g, char* l) {
    __builtin_amdgcn_global_load_lds(
        (const __attribute__((address_space(1))) void*)g,
        (__attribute__((address_space(3))) void*)l, 16, 0, 0);
}

// ---------------------------------------------------------------------------
// Merged pre-pass (unchanged from r10). Blocks [0, TR_BLOCKS): NCHW fp32 ->
// xt[n][h'][w'][ic] bf16 padded, halo zeroed. Blocks [TR_BLOCKS, +256): wt.
// ---------------------------------------------------------------------------
__global__ __launch_bounds__(256) void k_pre(const float* __restrict__ x,
                                             const float* __restrict__ wgt,
                                             const float* __restrict__ msk,
                                             unsigned short* __restrict__ xt,
                                             unsigned short* __restrict__ wt) {
    int t = threadIdx.x;
    if (blockIdx.x >= TR_BLOCKS) {
        int g = (blockIdx.x - TR_BLOCKS) * 256 + t; // g = oc*256 + ic
        const float* wp = wgt + (size_t)g * 9;
        const float* mp = msk + (size_t)g * 9;
#pragma unroll
        for (int tap = 0; tap < 9; ++tap)
            wt[(size_t)tap * (COUT * CIN) + g] = f2bf(wp[tap] * mp[tap]);
        return;
    }
    int b   = blockIdx.x;
    int icb = b & 3;
    int hp  = (b >> 2) % HP;
    int n   = b / (4 * HP);
    unsigned short* rowb = xt + ((size_t)(n * HP + hp) * WP) * CIN + icb * 64;

    if (hp == 0 || hp == HP - 1) {
        for (int idx = t; idx < WP * 8; idx += 256) {
            int wq = idx >> 3, q = idx & 7;
            *(uint4*)(rowb + (size_t)wq * CIN + q * 8) = (uint4){0, 0, 0, 0};
        }
        return;
    }
    int h = hp - 1;
    __shared__ __align__(16) char lds[64 * 128];
    int w = t & 63, icl0 = t >> 6;
    if (w < WW) {
        const float* src = x + ((size_t)(n * CIN + icb * 64 + icl0) * HH + h) * WW + w;
#pragma unroll
        for (int j = 0; j < 16; ++j) {
            float v = src[(size_t)(j * 4) * PIXIMG];
            int icl = icl0 + j * 4;
            *(unsigned short*)(lds + w * 128 + ((icl * 2) ^ ((w & 7) << 4))) = f2bf(v);
        }
    }
    __syncthreads();
    int ic4 = t & 15, wr = t >> 4;
    unsigned short* dst = rowb + (size_t)CIN + ic4 * 4;
#pragma unroll
    for (int p = 0; p < 4; ++p) {
        int w2 = wr + p * 16;
        if (w2 < WW) {
            uint2 v = *(const uint2*)(lds + w2 * 128 + ((ic4 * 8) ^ ((w2 & 7) << 4)));
            *(uint2*)(dst + (size_t)w2 * CIN) = v;
        }
    }
    if (t < 32) {
        int col = (t >> 4) * (WP - 1);
        *(uint2*)(rowb + (size_t)col * CIN + (t & 15) * 4) = (uint2){0, 0};
    }
}

// ---------------------------------------------------------------------------
// Main conv, halo-B-reuse structure. GEMM pixel axis = PADDED 58x58 grid (q);
// tap (dh,dw) is then a constant LDS-row shift delta=(dh-1)*58+(dw-1).
// Per 128-position tile: loop icb(4) { stage B' halo range [q0-59, q0+189)
// = 248 rows x 64ic ONCE; loop tap(9) { stage A[tap][128oc][64ic]; sync;
// 32 MFMA with B rows shifted by delta; sync } }. B staged 1x instead of 9x:
// per-step drain payload halves (A only, 4 gl16/wave), total staged bytes
// -39%. Cost: 7.3% halo positions computed then discarded by predicated
// epilogue. Drain-style loop kept (r5-proven); LDS 47KB -> 3 blocks/CU.
// ---------------------------------------------------------------------------
__global__ __launch_bounds__(256, 3) void k_conv(const unsigned short* __restrict__ xt,
                                                 const unsigned short* __restrict__ wt,
                                                 float* __restrict__ out) {
    __shared__ __align__(16) char lds[48128]; // A [128][128B] @0, B' [248][128B] @16384

    const int t    = threadIdx.x;
    const int lane = t & 63;
    const int wid  = t >> 6;
    const int woc  = wid >> 1; // 64-oc half
    const int wpx  = wid & 1;  // 64-pix half

    // bijective XCD swizzle: 1682 = 8*210 + 2
    const int xcd = blockIdx.x & 7;
    const int idx = blockIdx.x >> 3;
    const int wg  = (xcd < 2) ? xcd * 211 + idx : 422 + (xcd - 2) * 210 + idx;
    const int ptile = wg >> 1;
    const int ocb   = wg & 1;
    const int q0    = ptile * 128;

    // ---- staging lane decomposition (shared by A and B'): 8 rows x 8 slots ----
    const int rl = lane >> 3;                    // row-in-chunk 0..7
    const int sc = ((lane & 7) ^ rl) * 8;        // inverse-swizzled src col (elems)

    // A: per (tap,icb) stage rows [wid*32, +32) as 4 chunks of 8 rows
    const unsigned short* aS[4];
    char* dA[4];
#pragma unroll
    for (int c = 0; c < 4; ++c) {
        int r = wid * 32 + c * 8 + rl;
        aS[c] = wt + (size_t)(ocb * 128 + r) * CIN + sc;
        dA[c] = lds + (wid * 32 + c * 8) * 128;
    }

    // ---- fragment read offsets ----
    const int l15  = lane & 15;
    const int lg   = lane >> 4;
    const int swzf = (lane & 7) << 4;
    int colk[2];
    colk[0] = (lg * 16) ^ swzf;
    colk[1] = (64 + lg * 16) ^ swzf;
    int rowA[4];
#pragma unroll
    for (int i = 0; i < 4; ++i)
        rowA[i] = (woc * 64 + i * 16 + l15) * 128;

    float4v acc[4][4];
#pragma unroll
    for (int i = 0; i < 4; ++i)
#pragma unroll
        for (int j = 0; j < 4; ++j)
            acc[i][j] = (float4v){0.f, 0.f, 0.f, 0.f};

    // ---- main loop: 4 ic-blocks x 9 taps ----
#pragma unroll 1
    for (int icb = 0; icb < 4; ++icb) {
        // stage B' once: 31 chunks of 8 rows; clamp ends (clamped rows unused)
        for (int k = wid; k < 31; k += 4) {
            int qr = q0 - 59 + 8 * k;
            qr = (qr < 0) ? 0 : ((qr > QTOT - 8) ? QTOT - 8 : qr);
            gl16(xt + (size_t)(qr + rl) * CIN + icb * 64 + sc,
                 lds + 16384 + k * 1024);
        }
#pragma unroll
        for (int tap = 0; tap < 9; ++tap) {
            const size_t ao = (size_t)tap * (COUT * CIN) + icb * 64;
#pragma unroll
            for (int c = 0; c < 4; ++c) gl16(aS[c] + ao, dA[c]);
            __syncthreads(); // drain (A now; +B' at tap 0) + barrier
            const int dh    = (tap * 86) >> 8;
            const int dw    = tap - dh * 3;
            const int delta = (dh - 1) * WP + (dw - 1); // -59..+59
            const int rbb   = 59 + delta + wpx * 64 + l15;
#pragma unroll
            for (int kk = 0; kk < 2; ++kk) {
                short8 af[4], bf[4];
#pragma unroll
                for (int i = 0; i < 4; ++i)
                    af[i] = *(const short8*)(lds + rowA[i] + colk[kk]);
#pragma unroll
                for (int i = 0; i < 4; ++i) {
                    int rb = rbb + i * 16;
                    bf[i] = *(const short8*)(lds + 16384 + rb * 128 +
                                             ((kk * 64 + lg * 16) ^ ((rb & 7) << 4)));
                }
#pragma unroll
                for (int oi = 0; oi < 4; ++oi)
#pragma unroll
                    for (int pi = 0; pi < 4; ++pi)
                        acc[oi][pi] = __builtin_amdgcn_mfma_f32_16x16x32_bf16(
                            af[oi], bf[pi], acc[oi][pi], 0, 0, 0);
            }
            __syncthreads(); // reads retired before next overwrite
        }
    }

    // ---- epilogue: LDS transpose + predicated stores (halo cols dropped) ----
    float* ep = (float*)lds; // [64 oc][132] f32
    const int rcol = (t & 31) * 4;
    bool vld[4];
    float* obase[4];
#pragma unroll
    for (int cc = 0; cc < 4; ++cc) {
        int q  = q0 + rcol + cc;
        int n  = q / QIMG;
        int r2 = q - n * QIMG;
        int hp = r2 / WP;
        int wp = r2 - hp * WP;
        vld[cc] = ((unsigned)(hp - 1) < (unsigned)HH) &&
                  ((unsigned)(wp - 1) < (unsigned)WW);
        obase[cc] = out + (size_t)n * OUTSTRIDE_N +
                    (size_t)(ocb * 128) * PIXIMG + (hp - 1) * WW + (wp - 1);
    }
#pragma unroll 1
    for (int c = 0; c < 2; ++c) {
        if (woc == c) {
#pragma unroll
            for (int oi = 0; oi < 4; ++oi)
#pragma unroll
                for (int pi = 0; pi < 4; ++pi)
#pragma unroll
                    for (int r = 0; r < 4; ++r)
                        ep[(oi * 16 + lg * 4 + r) * 132 +
                           (wpx * 64 + pi * 16 + l15)] = acc[oi][pi][r];
        }
        __syncthreads();
        const int rrow = t >> 5; // 0..7
#pragma unroll
        for (int rd = 0; rd < 8; ++rd) {
            int row = rd * 8 + rrow; // 0..63
            float4v v = *(const float4v*)&ep[row * 132 + rcol];
            size_t ro = (size_t)(c * 64 + row) * PIXIMG;
#pragma unroll
            for (int cc = 0; cc < 4; ++cc)
                if (vld[cc]) obase[cc][ro] = v[cc];
        }
        __syncthreads(); // chunk reads done before next chunk's writes
    }
}

// ---------------------------------------------------------------------------
// Fallback (ws too small): direct fp32 conv, slow but correct
// ---------------------------------------------------------------------------
__global__ __launch_bounds__(256) void k_naive(const float* __restrict__ x,
                                               const float* __restrict__ wg,
                                               const float* __restrict__ mk,
                                               float* __restrict__ out, int total) {
    int idx = blockIdx.x * 256 + threadIdx.x;
    if (idx >= total) return;
    int w  = idx % WW;
    int h  = (idx / WW) % HH;
    int oc = (idx / PIXIMG) % COUT;
    int n  = idx / (COUT * PIXIMG);
    float s = 0.f;
    for (int ic = 0; ic < CIN; ++ic) {
        const float* xp = x + (size_t)(n * CIN + ic) * PIXIMG;
        const float* wp = wg + (size_t)(oc * CIN + ic) * 9;
        const float* mp = mk + (size_t)(oc * CIN + ic) * 9;
#pragma unroll
        for (int kh = 0; kh < 3; ++kh) {
            int hy = h + kh - 1;
            if ((unsigned)hy >= HH) continue;
#pragma unroll
            for (int kw = 0; kw < 3; ++kw) {
                int wx = w + kw - 1;
                if ((unsigned)wx >= WW) continue;
                s += xp[hy * WW + wx] * wp[kh * 3 + kw] * mp[kh * 3 + kw];
            }
        }
    }
    out[idx] = s;
}

extern "C" void kernel_launch(void* const* d_in, const int* in_sizes, int n_in,
                              void* d_out, int out_size, void* d_ws, size_t ws_size,
                              hipStream_t stream) {
    const float* x  = (const float*)d_in[0];
    const float* wg = (const float*)d_in[1];
    const float* mk = (const float*)d_in[2];
    float* out = (float*)d_out;

    size_t need = XT_ELEMS * 2 + WT_ELEMS * 2 + 256;
    if (ws_size < need) {
        int total = NIMG * COUT * PIXIMG;
        k_naive<<<(total + 255) / 256, 256, 0, stream>>>(x, wg, mk, out, total);
        return;
    }

    unsigned short* xt = (unsigned short*)d_ws;
    unsigned short* wt = (unsigned short*)((char*)d_ws + XT_ELEMS * 2);

    k_pre<<<TR_BLOCKS + (COUT * CIN) / 256, 256, 0, stream>>>(x, wg, mk, xt, wt);
    k_conv<<<NTILE * 2, 256, 0, stream>>>(xt, wt, out);
}

// Round 12
// 151.489 us; speedup vs baseline: 1.0285x; 1.0285x over previous
//
#include <hip/hip_runtime.h>
#include <hip/hip_bf16.h>

typedef short short8 __attribute__((ext_vector_type(8)));
typedef float float4v __attribute__((ext_vector_type(4)));

#define NIMG 32
#define CIN 256
#define COUT 256
#define HH 56
#define WW 56
#define HP 58
#define WP 58
#define PIXIMG (HH * WW)          /* 3136 */
#define TOTPIX (NIMG * PIXIMG)    /* 100352 */
#define OUTSTRIDE_N (COUT * PIXIMG)
#define TR_BLOCKS (NIMG * HP * 4) /* 7424 transpose blocks in k_pre */

static constexpr size_t XT_ELEMS = (size_t)NIMG * HP * WP * CIN; // bf16
static constexpr size_t WT_ELEMS = (size_t)9 * COUT * CIN;       // bf16

// fp32 -> bf16 bits, round-to-nearest-even (finite inputs only)
static __device__ __forceinline__ unsigned short f2bf(float f) {
    unsigned int u = __builtin_bit_cast(unsigned int, f);
    u = (u + 0x7fffu + ((u >> 16) & 1u)) >> 16;
    return (unsigned short)u;
}

// async global(16B/lane) -> LDS (wave-uniform base + lane*16)
static __device__ __forceinline__ void gl16(const unsigned short* g, char* l) {
    __builtin_amdgcn_global_load_lds(
        (const __attribute__((address_space(1))) void*)g,
        (__attribute__((address_space(3))) void*)l, 16, 0, 0);
}

// ---------------------------------------------------------------------------
// Merged pre-pass. Blocks [0, TR_BLOCKS): x NCHW fp32 -> x_t[n][h'][w'][ic]
// bf16 (padded, halo zeroed in-kernel). Blocks [TR_BLOCKS, +256):
// wt[tap][oc][ic] = bf16(weight*mask). Runs at ~5.6 TB/s ~= 89% of
// achievable HBM (ideal traffic 158 MB -> 25 us floor): memory roofline.
// ---------------------------------------------------------------------------
__global__ __launch_bounds__(256) void k_pre(const float* __restrict__ x,
                                             const float* __restrict__ wgt,
                                             const float* __restrict__ msk,
                                             unsigned short* __restrict__ xt,
                                             unsigned short* __restrict__ wt) {
    int t = threadIdx.x;
    if (blockIdx.x >= TR_BLOCKS) {
        // ---- prepw part ----
        int g = (blockIdx.x - TR_BLOCKS) * 256 + t; // g = oc*256 + ic
        const float* wp = wgt + (size_t)g * 9;
        const float* mp = msk + (size_t)g * 9;
#pragma unroll
        for (int tap = 0; tap < 9; ++tap)
            wt[(size_t)tap * (COUT * CIN) + g] = f2bf(wp[tap] * mp[tap]);
        return;
    }
    // ---- transpose part ----
    int b   = blockIdx.x;
    int icb = b & 3;
    int hp  = (b >> 2) % HP;    // padded output row 0..57
    int n   = b / (4 * HP);
    unsigned short* rowb = xt + ((size_t)(n * HP + hp) * WP) * CIN + icb * 64;

    if (hp == 0 || hp == HP - 1) {
        for (int idx = t; idx < WP * 8; idx += 256) {
            int wq = idx >> 3, q = idx & 7;
            *(uint4*)(rowb + (size_t)wq * CIN + q * 8) = (uint4){0, 0, 0, 0};
        }
        return;
    }
    int h = hp - 1;
    __shared__ __align__(16) char lds[64 * 128]; // [w 64][ic 64] bf16, swizzled
    int w = t & 63, icl0 = t >> 6;
    if (w < WW) {
        const float* src = x + ((size_t)(n * CIN + icb * 64 + icl0) * HH + h) * WW + w;
#pragma unroll
        for (int j = 0; j < 16; ++j) {
            float v = src[(size_t)(j * 4) * PIXIMG];
            int icl = icl0 + j * 4;
            *(unsigned short*)(lds + w * 128 + ((icl * 2) ^ ((w & 7) << 4))) = f2bf(v);
        }
    }
    __syncthreads();
    int ic4 = t & 15, wr = t >> 4;
    unsigned short* dst = rowb + (size_t)CIN + ic4 * 4; // w'=1 base
#pragma unroll
    for (int p = 0; p < 4; ++p) {
        int w2 = wr + p * 16;
        if (w2 < WW) {
            uint2 v = *(const uint2*)(lds + w2 * 128 + ((ic4 * 8) ^ ((w2 & 7) << 4)));
            *(uint2*)(dst + (size_t)w2 * CIN) = v;
        }
    }
    if (t < 32) { // zero w'=0 and w'=57 columns
        int col = (t >> 4) * (WP - 1);
        *(uint2*)(rowb + (size_t)col * CIN + (t & 15) * 4) = (uint2){0, 0};
    }
}

// ---------------------------------------------------------------------------
// Main conv (champion): 9 shifted GEMMs, m97 structure: 128x128 tile,
// 4 waves (2x2), BK=64, SINGLE 32KB A+B buffer, {STAGE; sync; COMP; sync}
// per K-step, 12 waves/CU; cross-block wave overlap absorbs the per-step
// vmcnt(0) drains (m114 regime). Measured: 122.6 us = 968 TF = 39% dense
// peak = the documented plain-HIP 2-barrier structural ceiling.
// Falsified alternatives on THIS problem: 2-phase dbuf 141 (r2), 8-phase
// counted-vmcnt 175/176 (r3/r4), BK=32 counted-vmcnt 158/160 (r8/r9),
// halo-B-reuse 134 (r11: FETCH -66% but steps are LATENCY-bound -> payload
// cut buys nothing, +7.3% halo MFMA loses). Occupancy is register-capped
// (60 arch VGPR + 64 AGPR acc, unified file); LDS pipelining attempts can't
// beat the drain because the wait is the last load's L2 round-trip.
// ---------------------------------------------------------------------------
__global__ __launch_bounds__(256, 4) void k_conv(const unsigned short* __restrict__ xt,
                                                 const unsigned short* __restrict__ wt,
                                                 float* __restrict__ out) {
    __shared__ __align__(16) char lds[64 * 132 * 4]; // 33792 B
    // K-loop uses first 32KB: A [128 oc][64 ic] @0, B [128 pix][64 ic] @16384

    const int t    = threadIdx.x;
    const int lane = t & 63;
    const int wid  = t >> 6;
    const int woc  = wid >> 1; // 64-oc half
    const int wpx  = wid & 1;  // 64-pix half

    // XCD-aware chunked swizzle: 1568 blocks = 8 XCDs x 196
    const int b0 = blockIdx.x;
    const int b  = (b0 & 7) * 196 + (b0 >> 3);
    const int ptile = b >> 1;
    const int ocb   = b & 1;

    // ---- staging: wave stages rows [wid*32, +32) of A and B; 4 gl16 each ----
    const int rl  = lane >> 3;                 // row-within-8 at dest
    const int sc  = ((lane & 7) ^ rl) * 8;     // inverse-swizzled src col (elems)
    const unsigned short* aS[4];
    const unsigned short* bS[4];
    char* dA[4];
    char* dB[4];
#pragma unroll
    for (int c = 0; c < 4; ++c) {
        int r = wid * 32 + c * 8 + rl;
        aS[c] = wt + (size_t)(ocb * 128 + r) * CIN + sc;
        int pg  = ptile * 128 + r;
        int n   = pg / PIXIMG;
        int rem = pg - n * PIXIMG;
        int h   = rem / WW, w = rem - h * WW;
        bS[c] = xt + ((size_t)((n * HP + h) * WP + w)) * CIN + sc;
        dA[c] = lds + (wid * 32 + c * 8) * 128;
        dB[c] = lds + 16384 + (wid * 32 + c * 8) * 128;
    }

    // ---- fragment read offsets ----
    const int l15  = lane & 15;
    const int lg   = lane >> 4;
    const int swzf = (lane & 7) << 4;
    int colk[2];
    colk[0] = (lg * 16) ^ swzf;
    colk[1] = (64 + lg * 16) ^ swzf;
    int rowA[4], rowB[4];
#pragma unroll
    for (int i = 0; i < 4; ++i) {
        rowA[i] = (woc * 64 + i * 16 + l15) * 128;
        rowB[i] = 16384 + (wpx * 64 + i * 16 + l15) * 128;
    }

    float4v acc[4][4];
#pragma unroll
    for (int i = 0; i < 4; ++i)
#pragma unroll
        for (int j = 0; j < 4; ++j)
            acc[i][j] = (float4v){0.f, 0.f, 0.f, 0.f};

    // ---- main loop: 36 K-steps, single-buffered (m97 structure) ----
#pragma unroll 1
    for (int s = 0; s < 36; ++s) {
        const int tap = s >> 2;
        const int dh  = (tap * 86) >> 8;
        const int dw  = tap - dh * 3;
        const size_t ao = (size_t)tap * (COUT * CIN) + (size_t)((s & 3) << 6);
        const size_t bo = (size_t)(dh * WP + dw) * CIN + (size_t)((s & 3) << 6);
#pragma unroll
        for (int c = 0; c < 4; ++c) gl16(aS[c] + ao, dA[c]);
#pragma unroll
        for (int c = 0; c < 4; ++c) gl16(bS[c] + bo, dB[c]);
        __syncthreads(); // vmcnt(0) drain + barrier: buffer ready
#pragma unroll
        for (int kk = 0; kk < 2; ++kk) {
            short8 af[4], bfr[4];
#pragma unroll
            for (int i = 0; i < 4; ++i)
                af[i] = *(const short8*)(lds + rowA[i] + colk[kk]);
#pragma unroll
            for (int i = 0; i < 4; ++i)
                bfr[i] = *(const short8*)(lds + rowB[i] + colk[kk]);
#pragma unroll
            for (int oi = 0; oi < 4; ++oi)
#pragma unroll
                for (int pi = 0; pi < 4; ++pi)
                    acc[oi][pi] = __builtin_amdgcn_mfma_f32_16x16x32_bf16(
                        af[oi], bfr[pi], acc[oi][pi], 0, 0, 0);
        }
        __syncthreads(); // reads done before next stage overwrites
    }

    // ---- epilogue: 2 chunks of 64 oc via LDS transpose, coalesced stores ----
    float* ep = (float*)lds; // [64 oc][132] f32, pad kills write conflicts
#pragma unroll 1
    for (int c = 0; c < 2; ++c) {
        if (woc == c) {
#pragma unroll
            for (int oi = 0; oi < 4; ++oi)
#pragma unroll
                for (int pi = 0; pi < 4; ++pi)
#pragma unroll
                    for (int r = 0; r < 4; ++r)
                        ep[(oi * 16 + lg * 4 + r) * 132 +
                           (wpx * 64 + pi * 16 + l15)] = acc[oi][pi][r];
        }
        __syncthreads();
        const int rrow = t >> 5;        // 0..7
        const int rcol = (t & 31) * 4;  // 0..124
        int pg  = ptile * 128 + rcol;
        int n2  = pg / PIXIMG;
        int rem = pg - n2 * PIXIMG;     // 3136%4==0: float4 stays in-image
        float* ob = out + (size_t)n2 * OUTSTRIDE_N +
                    (size_t)(ocb * 128 + c * 64) * PIXIMG + rem;
#pragma unroll
        for (int rd = 0; rd < 8; ++rd) {
            int row = rd * 8 + rrow;    // 0..63
            float4v v = *(const float4v*)&ep[row * 132 + rcol];
            *(float4v*)(ob + (size_t)row * PIXIMG) = v;
        }
        __syncthreads(); // chunk reads done before next chunk's writes
    }
}

// ---------------------------------------------------------------------------
// Fallback (ws too small): direct fp32 conv, slow but correct
// ---------------------------------------------------------------------------
__global__ __launch_bounds__(256) void k_naive(const float* __restrict__ x,
                                               const float* __restrict__ wg,
                                               const float* __restrict__ mk,
                                               float* __restrict__ out, int total) {
    int idx = blockIdx.x * 256 + threadIdx.x;
    if (idx >= total) return;
    int w  = idx % WW;
    int h  = (idx / WW) % HH;
    int oc = (idx / PIXIMG) % COUT;
    int n  = idx / (COUT * PIXIMG);
    float s = 0.f;
    for (int ic = 0; ic < CIN; ++ic) {
        const float* xp = x + (size_t)(n * CIN + ic) * PIXIMG;
        const float* wp = wg + (size_t)(oc * CIN + ic) * 9;
        const float* mp = mk + (size_t)(oc * CIN + ic) * 9;
#pragma unroll
        for (int kh = 0; kh < 3; ++kh) {
            int hy = h + kh - 1;
            if ((unsigned)hy >= HH) continue;
#pragma unroll
            for (int kw = 0; kw < 3; ++kw) {
                int wx = w + kw - 1;
                if ((unsigned)wx >= WW) continue;
                s += xp[hy * WW + wx] * wp[kh * 3 + kw] * mp[kh * 3 + kw];
            }
        }
    }
    out[idx] = s;
}

extern "C" void kernel_launch(void* const* d_in, const int* in_sizes, int n_in,
                              void* d_out, int out_size, void* d_ws, size_t ws_size,
                              hipStream_t stream) {
    const float* x  = (const float*)d_in[0];
    const float* wg = (const float*)d_in[1];
    const float* mk = (const float*)d_in[2];
    float* out = (float*)d_out;

    size_t need = XT_ELEMS * 2 + WT_ELEMS * 2 + 256;
    if (ws_size < need) {
        int total = NIMG * COUT * PIXIMG;
        k_naive<<<(total + 255) / 256, 256, 0, stream>>>(x, wg, mk, out, total);
        return;
    }

    unsigned short* xt = (unsigned short*)d_ws;
    unsigned short* wt = (unsigned short*)((char*)d_ws + XT_ELEMS * 2);

    k_pre<<<TR_BLOCKS + (COUT * CIN) / 256, 256, 0, stream>>>(x, wg, mk, xt, wt);
    k_conv<<<(TOTPIX / 128) * 2, 256, 0, stream>>>(xt, wt, out);
}